// Round 13
// baseline (109.365 us; speedup 1.0000x reference)
//
#include <hip/hip_runtime.h>

#define BN 2
#define T_DIM 2048
#define D_DIM 1024
#define H_N 16
#define DH_N 64
#define WIN 256
#define NROWS (BN * T_DIM)   // 4096
#define KDIM 1024            // inner dim for all GEMMs

typedef __attribute__((ext_vector_type(8))) short bf16x8;
typedef __attribute__((ext_vector_type(4))) float f32x4;
typedef __attribute__((ext_vector_type(8))) unsigned short ushort8;
typedef __attribute__((ext_vector_type(4))) unsigned short u16x4;

static __device__ __forceinline__ unsigned short f2bf(float f) {
  unsigned int u = __float_as_uint(f);
  unsigned int r = (u + 0x7FFFu + ((u >> 16) & 1u)) >> 16;  // RNE
  return (unsigned short)r;
}

static __device__ __forceinline__ void gl_lds16(const void* g, void* l) {
  __builtin_amdgcn_global_load_lds(
      (const __attribute__((address_space(1))) unsigned int*)g,
      (__attribute__((address_space(3))) unsigned int*)l, 16, 0, 0);
}

#define MFMA16(a, b, c) __builtin_amdgcn_mfma_f32_16x16x32_bf16(a, b, c, 0, 0, 0)

// ---------------------------------------------------------------------------
// Merged conversions (one launch): x f32->bf16 (blocks 0..2047),
// w_qkv^T (2048..2815), w_out^T (2816..3071).
// ---------------------------------------------------------------------------
static __device__ __forceinline__ void transpose_tile(
    const float* __restrict__ src, unsigned short* __restrict__ dst, int R,
    int C, int bx, int by, float* tile /* [64][65] */) {
  const int t = threadIdx.x;
  const int bc = bx * 64, br = by * 64;
#pragma unroll
  for (int i = 0; i < 16; ++i) {
    int idx = i * 256 + t;
    int r = idx >> 6, c = idx & 63;
    tile[r * 65 + c] = src[(size_t)(br + r) * C + bc + c];
  }
  __syncthreads();
#pragma unroll
  for (int i = 0; i < 16; ++i) {
    int idx = i * 256 + t;
    int r = idx >> 6, c = idx & 63;
    dst[(size_t)(bc + r) * R + br + c] = f2bf(tile[c * 65 + r]);
  }
}

__global__ __launch_bounds__(256) void convert_all(
    const float* __restrict__ x, const float* __restrict__ w_qkv,
    const float* __restrict__ w_out, unsigned short* __restrict__ xbf,
    unsigned short* __restrict__ wqkvt, unsigned short* __restrict__ woutt) {
  __shared__ float tile[64 * 65];
  const int id = blockIdx.x;
  if (id < 2048) {
    int i = (id * 256 + threadIdx.x) * 8;
    float4 a = *(const float4*)(x + i);
    float4 b = *(const float4*)(x + i + 4);
    ushort8 o;
    o[0] = f2bf(a.x); o[1] = f2bf(a.y); o[2] = f2bf(a.z); o[3] = f2bf(a.w);
    o[4] = f2bf(b.x); o[5] = f2bf(b.y); o[6] = f2bf(b.z); o[7] = f2bf(b.w);
    *(ushort8*)(xbf + i) = o;
  } else if (id < 2816) {
    int j = id - 2048;  // 48 x 16
    transpose_tile(w_qkv, wqkvt, D_DIM, 3 * D_DIM, j % 48, j / 48, tile);
  } else {
    int j = id - 2816;  // 16 x 16
    transpose_tile(w_out, woutt, D_DIM, D_DIM, j % 16, j / 16, tile);
  }
}

// ---------------------------------------------------------------------------
// qkv GEMM (measured-best, 41.4us): 256x192 tile, grid 256 blocks, 8 waves,
// BK=64, double-buffered 112KB LDS, 4 phases/K-tile, counted vmcnt(2),
// XOR swizzle slot^(row&7) both sides.
// Epilogue: q,k bf16 [B,H,T,64] (q*0.125), v^T bf16 [B,H,64,T].
// ---------------------------------------------------------------------------
__global__ __launch_bounds__(512) void gemm_qkv_8p(
    const unsigned short* __restrict__ A, const unsigned short* __restrict__ Bt,
    const float* __restrict__ bias, unsigned short* __restrict__ qo,
    unsigned short* __restrict__ ko, unsigned short* __restrict__ vto) {
  __shared__ unsigned short As[2][256 * 64];  // 2 x 32 KB
  __shared__ unsigned short Bs[2][192 * 64];  // 2 x 24 KB

  const int tid = threadIdx.x;
  const int w = tid >> 6, l = tid & 63;
  const int wr = w >> 2, wc = w & 3;  // 2M x 4N waves, per-wave 128x48
  const int l15 = l & 15, kslc = l >> 4;

  const int id = blockIdx.x;
  const int wg = (id & 7) * 32 + (id >> 3);
  const int bx = wg & 15, by = wg >> 4;
  const int r0 = by * 256, c0 = bx * 192;

  const unsigned short* Ag = A + (size_t)r0 * KDIM;
  const unsigned short* Bg = Bt + (size_t)c0 * KDIM;

  f32x4 acc[8][3];
#pragma unroll
  for (int i = 0; i < 8; ++i)
#pragma unroll
    for (int j = 0; j < 3; ++j) acc[i][j] = (f32x4){0.f, 0.f, 0.f, 0.f};

  const int grow = tid >> 3;                 // row within 64-row chunk
  const int gcol = (tid & 7) ^ (grow & 7);   // pre-swizzled source slot

#define STAGE_A(T, BUF, CH)                                                    \
  gl_lds16(Ag + (size_t)((CH)*64 + grow) * KDIM + (T)*64 + gcol * 8,           \
           (char*)&As[BUF][0] + (CH)*8192 + w * 1024)
#define STAGE_B(T, BUF, CH)                                                    \
  gl_lds16(Bg + (size_t)((CH)*64 + grow) * KDIM + (T)*64 + gcol * 8,           \
           (char*)&Bs[BUF][0] + (CH)*8192 + w * 1024)

#define LDA(CB, mi, ks)                                                        \
  (*(const bf16x8*)((const char*)&As[CB][0] +                                  \
                    (wr * 128 + (mi)*16 + l15) * 128 +                         \
                    ((((ks)*4 + kslc) ^ (l15 & 7)) << 4)))
#define LDB(CB, ni, ks)                                                        \
  (*(const bf16x8*)((const char*)&Bs[CB][0] +                                  \
                    (wc * 48 + (ni)*16 + l15) * 128 +                          \
                    ((((ks)*4 + kslc) ^ (l15 & 7)) << 4)))

#define CLUSTER12(B_, A0, A1, A2, A3, B0, B1, B2)                              \
  do {                                                                         \
    __builtin_amdgcn_s_setprio(1);                                             \
    acc[B_ + 0][0] = MFMA16(A0, B0, acc[B_ + 0][0]);                           \
    acc[B_ + 0][1] = MFMA16(A0, B1, acc[B_ + 0][1]);                           \
    acc[B_ + 0][2] = MFMA16(A0, B2, acc[B_ + 0][2]);                           \
    acc[B_ + 1][0] = MFMA16(A1, B0, acc[B_ + 1][0]);                           \
    acc[B_ + 1][1] = MFMA16(A1, B1, acc[B_ + 1][1]);                           \
    acc[B_ + 1][2] = MFMA16(A1, B2, acc[B_ + 1][2]);                           \
    acc[B_ + 2][0] = MFMA16(A2, B0, acc[B_ + 2][0]);                           \
    acc[B_ + 2][1] = MFMA16(A2, B1, acc[B_ + 2][1]);                           \
    acc[B_ + 2][2] = MFMA16(A2, B2, acc[B_ + 2][2]);                           \
    acc[B_ + 3][0] = MFMA16(A3, B0, acc[B_ + 3][0]);                           \
    acc[B_ + 3][1] = MFMA16(A3, B1, acc[B_ + 3][1]);                           \
    acc[B_ + 3][2] = MFMA16(A3, B2, acc[B_ + 3][2]);                           \
    __builtin_amdgcn_s_setprio(0);                                             \
  } while (0)

  STAGE_A(0, 0, 0); STAGE_A(0, 0, 1); STAGE_A(0, 0, 2); STAGE_A(0, 0, 3);
  STAGE_B(0, 0, 0); STAGE_B(0, 0, 1); STAGE_B(0, 0, 2);

#pragma unroll 1
  for (int t = 0; t < 15; ++t) {
    const int cb = t & 1, nb = cb ^ 1;
    STAGE_A(t + 1, nb, 0); STAGE_A(t + 1, nb, 1);
    asm volatile("s_waitcnt vmcnt(2)" ::: "memory");
    __builtin_amdgcn_s_barrier();
    {
      bf16x8 a0 = LDA(cb, 0, 0), a1 = LDA(cb, 1, 0), a2 = LDA(cb, 2, 0),
             a3 = LDA(cb, 3, 0);
      bf16x8 b0 = LDB(cb, 0, 0), b1 = LDB(cb, 1, 0), b2 = LDB(cb, 2, 0);
      CLUSTER12(0, a0, a1, a2, a3, b0, b1, b2);
      __builtin_amdgcn_s_barrier();
      bf16x8 a4 = LDA(cb, 4, 0), a5 = LDA(cb, 5, 0), a6 = LDA(cb, 6, 0),
             a7 = LDA(cb, 7, 0);
      STAGE_A(t + 1, nb, 2); STAGE_A(t + 1, nb, 3);
      __builtin_amdgcn_s_barrier();
      CLUSTER12(4, a4, a5, a6, a7, b0, b1, b2);
      __builtin_amdgcn_s_barrier();
      bf16x8 c0_ = LDA(cb, 0, 1), c1_ = LDA(cb, 1, 1), c2_ = LDA(cb, 2, 1),
             c3_ = LDA(cb, 3, 1);
      bf16x8 d0 = LDB(cb, 0, 1), d1 = LDB(cb, 1, 1), d2 = LDB(cb, 2, 1);
      STAGE_B(t + 1, nb, 0); STAGE_B(t + 1, nb, 1);
      __builtin_amdgcn_s_barrier();
      CLUSTER12(0, c0_, c1_, c2_, c3_, d0, d1, d2);
      __builtin_amdgcn_s_barrier();
      bf16x8 c4 = LDA(cb, 4, 1), c5 = LDA(cb, 5, 1), c6 = LDA(cb, 6, 1),
             c7 = LDA(cb, 7, 1);
      STAGE_B(t + 1, nb, 2);
      __builtin_amdgcn_s_barrier();
      CLUSTER12(4, c4, c5, c6, c7, d0, d1, d2);
      __builtin_amdgcn_s_barrier();
    }
  }
  asm volatile("s_waitcnt vmcnt(0)" ::: "memory");
  __builtin_amdgcn_s_barrier();
  {
    bf16x8 a0 = LDA(1, 0, 0), a1 = LDA(1, 1, 0), a2 = LDA(1, 2, 0),
           a3 = LDA(1, 3, 0);
    bf16x8 b0 = LDB(1, 0, 0), b1 = LDB(1, 1, 0), b2 = LDB(1, 2, 0);
    CLUSTER12(0, a0, a1, a2, a3, b0, b1, b2);
    bf16x8 a4 = LDA(1, 4, 0), a5 = LDA(1, 5, 0), a6 = LDA(1, 6, 0),
           a7 = LDA(1, 7, 0);
    CLUSTER12(4, a4, a5, a6, a7, b0, b1, b2);
    bf16x8 c0_ = LDA(1, 0, 1), c1_ = LDA(1, 1, 1), c2_ = LDA(1, 2, 1),
           c3_ = LDA(1, 3, 1);
    bf16x8 d0 = LDB(1, 0, 1), d1 = LDB(1, 1, 1), d2 = LDB(1, 2, 1);
    CLUSTER12(0, c0_, c1_, c2_, c3_, d0, d1, d2);
    bf16x8 c4 = LDA(1, 4, 1), c5 = LDA(1, 5, 1), c6 = LDA(1, 6, 1),
           c7 = LDA(1, 7, 1);
    CLUSTER12(4, c4, c5, c6, c7, d0, d1, d2);
  }
#undef STAGE_A
#undef STAGE_B
#undef LDA
#undef LDB
#undef CLUSTER12

#pragma unroll
  for (int ni = 0; ni < 3; ++ni) {
    const int col0 = c0 + wc * 48 + ni * 16;
    const int which = col0 >> 10;  // 0=q,1=k,2=v
    const int h = (col0 >> 6) & 15;
    const int dh = (col0 & 63) + l15;
    const float bv = bias[col0 + l15];
#pragma unroll
    for (int mi = 0; mi < 8; ++mi) {
      int row = r0 + wr * 128 + mi * 16 + (l >> 4) * 4;  // multiple of 4
      int b_ = row >> 11, t0 = row & 2047;
      if (which == 2) {
        u16x4 pk;
#pragma unroll
        for (int j = 0; j < 4; ++j) pk[j] = f2bf(acc[mi][ni][j] + bv);
        *(u16x4*)(vto + ((size_t)(b_ * H_N + h) * DH_N + dh) * T_DIM + t0) = pk;
      } else {
        float mul = (which == 0) ? 0.125f : 1.0f;
        unsigned short* dst = (which == 0) ? qo : ko;
#pragma unroll
        for (int j = 0; j < 4; ++j)
          dst[((size_t)(b_ * H_N + h) * T_DIM + t0 + j) * DH_N + dh] =
              f2bf((acc[mi][ni][j] + bv) * mul);
      }
    }
  }
}

// ---------------------------------------------------------------------------
// out-proj GEMM (unchanged): 128x128, quad-buffer, lead-2, one barrier/iter,
// counted vmcnt(8).
// ---------------------------------------------------------------------------
__global__ __launch_bounds__(256) void gemm_out_p4(
    const unsigned short* __restrict__ A, const unsigned short* __restrict__ Bt,
    const float* __restrict__ bias, float* __restrict__ fo) {
  __shared__ unsigned short As[4][4096];
  __shared__ unsigned short Bs[4][4096];

  const int tid = threadIdx.x;
  const int w = tid >> 6, l = tid & 63;
  const int wr = w >> 1, wc = w & 1;
  const int l15 = l & 15, kslc = l >> 4;

  const int id = blockIdx.x;
  const int wg = (id & 7) * 32 + (id >> 3);
  const int bx = wg & 7, by = wg >> 3;
  const int r0 = by * 128, c0 = bx * 128;

  const unsigned short* Ag = A + (size_t)r0 * KDIM;
  const unsigned short* Bg = Bt + (size_t)c0 * KDIM;

  f32x4 acc[4][4];
#pragma unroll
  for (int i = 0; i < 4; ++i)
#pragma unroll
    for (int j = 0; j < 4; ++j) acc[i][j] = (f32x4){0.f, 0.f, 0.f, 0.f};

  const int srow = l >> 2;
  const int srcslot = (l & 3) ^ ((l >> 3) & 3);

#define STAGE_O(T, BUF)                                                        \
  do {                                                                         \
    const size_t kk0 = (size_t)(T) * 32;                                       \
    gl_lds16(Ag + (size_t)(w * 16 + srow) * KDIM + kk0 + srcslot * 8,          \
             (char*)&As[BUF][0] + w * 1024);                                   \
    gl_lds16(Ag + (size_t)(64 + w * 16 + srow) * KDIM + kk0 + srcslot * 8,     \
             (char*)&As[BUF][0] + (4 + w) * 1024);                             \
    gl_lds16(Bg + (size_t)(w * 16 + srow) * KDIM + kk0 + srcslot * 8,          \
             (char*)&Bs[BUF][0] + w * 1024);                                   \
    gl_lds16(Bg + (size_t)(64 + w * 16 + srow) * KDIM + kk0 + srcslot * 8,     \
             (char*)&Bs[BUF][0] + (4 + w) * 1024);                             \
  } while (0)

#define OCOMPUTE(CB)                                                           \
  do {                                                                         \
    bf16x8 af[4], bfr[4];                                                      \
    _Pragma("unroll") for (int mi = 0; mi < 4; ++mi) {                         \
      int row = wr * 64 + mi * 16 + l15;                                       \
      af[mi] = *(const bf16x8*)((const char*)&As[CB][0] + row * 64 +           \
                                ((kslc ^ ((row >> 1) & 3)) << 4));             \
    }                                                                          \
    _Pragma("unroll") for (int ni = 0; ni < 4; ++ni) {                         \
      int row = wc * 64 + ni * 16 + l15;                                       \
      bfr[ni] = *(const bf16x8*)((const char*)&Bs[CB][0] + row * 64 +          \
                                 ((kslc ^ ((row >> 1) & 3)) << 4));            \
    }                                                                          \
    __builtin_amdgcn_s_setprio(1);                                             \
    _Pragma("unroll") for (int mi = 0; mi < 4; ++mi)                           \
        _Pragma("unroll") for (int ni = 0; ni < 4; ++ni) acc[mi][ni] =         \
            MFMA16(af[mi], bfr[ni], acc[mi][ni]);                              \
    __builtin_amdgcn_s_setprio(0);                                             \
  } while (0)

  STAGE_O(0, 0);
  STAGE_O(1, 1);

  for (int t = 0; t < 30; ++t) {
    STAGE_O(t + 2, (t + 2) & 3);
    asm volatile("s_waitcnt vmcnt(8)" ::: "memory");
    __builtin_amdgcn_s_barrier();
    OCOMPUTE(t & 3);
  }
  asm volatile("s_waitcnt vmcnt(4)" ::: "memory");
  __builtin_amdgcn_s_barrier();
  OCOMPUTE(2);
  asm volatile("s_waitcnt vmcnt(0)" ::: "memory");
  __builtin_amdgcn_s_barrier();
  OCOMPUTE(3);
#undef STAGE_O
#undef OCOMPUTE

#pragma unroll
  for (int mi = 0; mi < 4; ++mi) {
#pragma unroll
    for (int ni = 0; ni < 4; ++ni) {
      int row = r0 + wr * 64 + mi * 16 + (l >> 4) * 4;
      int col = c0 + wc * 64 + ni * 16 + l15;
      float bv = bias[col];
#pragma unroll
      for (int j = 0; j < 4; ++j)
        fo[(size_t)(row + j) * D_DIM + col] = acc[mi][ni][j] + bv;
    }
  }
}

// ---------------------------------------------------------------------------
// attn_direct: NO LDS, NO barriers. Every MFMA fragment is a per-lane
// contiguous 16B global load; K/V frags load global->VGPR through L1/L2.
// XCD map (FIXED, bijective): each XCD owns 4 whole (b,h) pairs
// (4 x 512KB = 2MB, L2-resident); all 32 q-tiles of a bh on one XCD.
//   bh = (bid&7)*4 + ((bid>>3)&3), qt = bid>>5.
// ---------------------------------------------------------------------------
__global__ __launch_bounds__(256) void attn_direct(
    const unsigned short* __restrict__ qbf,
    const unsigned short* __restrict__ kbf,
    const unsigned short* __restrict__ vtbf,
    unsigned short* __restrict__ ctx) {
  const int tid = threadIdx.x;
  const int w = tid >> 6, l = tid & 63;
  const int g = l >> 4, ln = l & 15;

  const int bid = blockIdx.x;
  const int r_ = bid >> 3;
  const int bh = (bid & 7) * 4 + (r_ & 3);   // 0..31  (8 XCD x 4 bh)
  const int qt = r_ >> 2;                    // 0..31
  const int q0 = qt * 64;
  const int q_abs = q0 + w * 16 + ln;

  const unsigned short* kp = kbf + (size_t)bh * T_DIM * DH_N;
  const unsigned short* vtp = vtbf + (size_t)bh * DH_N * T_DIM;

  bf16x8 qf0, qf1;
  {
    const unsigned short* qp = qbf + ((size_t)bh * T_DIM + q_abs) * DH_N;
    qf0 = *(const bf16x8*)(qp + g * 8);
    qf1 = *(const bf16x8*)(qp + 32 + g * 8);
  }

  // per-lane K row permutation (makes S^T lane layout == PV B-frag layout)
#define KAP(row) \
  (32 * (((row) >> 4) & 1) + 8 * (((row)&15) >> 2) + 4 * ((row) >> 5) + ((row)&3))
  const unsigned short* kbase[4];
#pragma unroll
  for (int nk = 0; nk < 4; ++nk) {
    int rrow = nk * 16 + ln;
    kbase[nk] = kp + (size_t)KAP(rrow) * DH_N + g * 8;
  }
  const unsigned short* vbase[4];
#pragma unroll
  for (int nd = 0; nd < 4; ++nd)
    vbase[nd] = vtp + (size_t)(nd * 16 + ln) * T_DIM + g * 8;
#undef KAP

  f32x4 acc_o[4];
#pragma unroll
  for (int nd = 0; nd < 4; ++nd) acc_o[nd] = (f32x4){0.f, 0.f, 0.f, 0.f};
  float m = -1e30f, lsum = 0.f;

  const int kt_lo = (q0 >= WIN) ? (q0 - WIN) : 0;
  for (int kt = kt_lo; kt <= q0; kt += 64) {
    // S^T = K . Q^T  (K-frags straight from global)
    f32x4 sacc[4];
#pragma unroll
    for (int nk = 0; nk < 4; ++nk) sacc[nk] = (f32x4){0.f, 0.f, 0.f, 0.f};
#pragma unroll
    for (int ks = 0; ks < 2; ++ks) {
      bf16x8 qf = ks ? qf1 : qf0;
#pragma unroll
      for (int nk = 0; nk < 4; ++nk) {
        bf16x8 kf = *(const bf16x8*)(kbase[nk] + (size_t)kt * DH_N + ks * 32);
        sacc[nk] = MFMA16(kf, qf, sacc[nk]);
      }
    }

    // mask + online softmax (lane owns one q-row)
    float p[4][4];
    float tm = -1e30f;
#pragma unroll
    for (int nk = 0; nk < 4; ++nk)
#pragma unroll
      for (int j = 0; j < 4; ++j) {
        int k_abs = kt + 32 * (nk & 1) + 8 * g + 4 * (nk >> 1) + j;
        float s = sacc[nk][j];
        bool ok = (k_abs <= q_abs) && (k_abs + WIN >= q_abs);
        s = ok ? s : -1e30f;
        p[nk][j] = s;
        tm = fmaxf(tm, s);
      }
    tm = fmaxf(tm, __shfl_xor(tm, 16, 64));
    tm = fmaxf(tm, __shfl_xor(tm, 32, 64));
    float mn = fmaxf(m, tm);
    float sc = __expf(m - mn);
    float ps = 0.f;
#pragma unroll
    for (int nk = 0; nk < 4; ++nk)
#pragma unroll
      for (int j = 0; j < 4; ++j) {
        p[nk][j] = __expf(p[nk][j] - mn);
        ps += p[nk][j];
      }
    ps += __shfl_xor(ps, 16, 64);
    ps += __shfl_xor(ps, 32, 64);
    lsum = lsum * sc + ps;
    m = mn;
#pragma unroll
    for (int nd = 0; nd < 4; ++nd) {
      acc_o[nd][0] *= sc; acc_o[nd][1] *= sc;
      acc_o[nd][2] *= sc; acc_o[nd][3] *= sc;
    }

    // pack P to bf16 (in-register; layout already matches PV B-frag)
    unsigned int pk[4][2];
#pragma unroll
    for (int nk = 0; nk < 4; ++nk) {
      pk[nk][0] = (unsigned)f2bf(p[nk][0]) | ((unsigned)f2bf(p[nk][1]) << 16);
      pk[nk][1] = (unsigned)f2bf(p[nk][2]) | ((unsigned)f2bf(p[nk][3]) << 16);
    }

    // O^T += V^T . P^T  (V-frags straight from global)
#pragma unroll
    for (int ks = 0; ks < 2; ++ks) {
      union { unsigned int d[4]; bf16x8 v; } pf;
      pf.d[0] = pk[ks][0];     pf.d[1] = pk[ks][1];
      pf.d[2] = pk[2 + ks][0]; pf.d[3] = pk[2 + ks][1];
#pragma unroll
      for (int nd = 0; nd < 4; ++nd) {
        bf16x8 vf = *(const bf16x8*)(vbase[nd] + kt + ks * 32);
        acc_o[nd] = MFMA16(vf, pf.v, acc_o[nd]);
      }
    }
  }

  float inv = 1.f / lsum;
  const int b_ = bh >> 4, h = bh & 15;
  unsigned short* op = ctx + ((size_t)b_ * T_DIM + q_abs) * D_DIM + h * DH_N;
#pragma unroll
  for (int nd = 0; nd < 4; ++nd) {
    u16x4 o;
#pragma unroll
    for (int j = 0; j < 4; ++j) o[j] = f2bf(acc_o[nd][j] * inv);
    *(u16x4*)(op + nd * 16 + g * 4) = o;
  }
}

// ---------------------------------------------------------------------------
extern "C" void kernel_launch(void* const* d_in, const int* in_sizes, int n_in,
                              void* d_out, int out_size, void* d_ws,
                              size_t ws_size, hipStream_t stream) {
  const float* x = (const float*)d_in[0];
  const float* w_qkv = (const float*)d_in[1];
  const float* b_qkv = (const float*)d_in[2];
  const float* w_out = (const float*)d_in[3];
  const float* b_out = (const float*)d_in[4];
  float* out = (float*)d_out;

  const size_t per = (size_t)BN * H_N * T_DIM * DH_N;  // 4,194,304
  unsigned short* qbf = (unsigned short*)d_ws;
  unsigned short* kbf = qbf + per;
  unsigned short* vtbf = kbf + per;                    // [B,H,64,T]
  unsigned short* xbf = vtbf + per;                    // [4096][1024]
  unsigned short* wqkvt = xbf + (size_t)NROWS * D_DIM; // [3072][1024]
  unsigned short* woutt = wqkvt + (size_t)3 * D_DIM * D_DIM;  // [1024][1024]
  unsigned short* ctxbf = woutt + (size_t)D_DIM * D_DIM;      // [4096][1024]

  convert_all<<<dim3(3072), dim3(256), 0, stream>>>(x, w_qkv, w_out, xbf,
                                                    wqkvt, woutt);

  gemm_qkv_8p<<<dim3(256), dim3(512), 0, stream>>>(xbf, wqkvt, b_qkv, qbf, kbf,
                                                   vtbf);

  attn_direct<<<dim3(BN * H_N * (T_DIM / 64)), dim3(256), 0, stream>>>(
      qbf, kbf, vtbf, ctxbf);

  gemm_out_p4<<<dim3(256), dim3(256), 0, stream>>>(ctxbf, woutt, b_out, out);
}

// Round 14
// 94.022 us; speedup vs baseline: 1.1632x; 1.1632x over previous
//
#include <hip/hip_runtime.h>

#define BN 2
#define T_DIM 2048
#define D_DIM 1024
#define H_N 16
#define DH_N 64
#define WIN 256
#define NROWS (BN * T_DIM)   // 4096
#define KDIM 1024            // inner dim for all GEMMs

typedef __attribute__((ext_vector_type(8))) short bf16x8;
typedef __attribute__((ext_vector_type(4))) float f32x4;
typedef __attribute__((ext_vector_type(8))) unsigned short ushort8;
typedef __attribute__((ext_vector_type(4))) unsigned short u16x4;

static __device__ __forceinline__ unsigned short f2bf(float f) {
  unsigned int u = __float_as_uint(f);
  unsigned int r = (u + 0x7FFFu + ((u >> 16) & 1u)) >> 16;  // RNE
  return (unsigned short)r;
}

static __device__ __forceinline__ void gl_lds16(const void* g, void* l) {
  __builtin_amdgcn_global_load_lds(
      (const __attribute__((address_space(1))) unsigned int*)g,
      (__attribute__((address_space(3))) unsigned int*)l, 16, 0, 0);
}

#define MFMA16(a, b, c) __builtin_amdgcn_mfma_f32_16x16x32_bf16(a, b, c, 0, 0, 0)

// ---------------------------------------------------------------------------
// Merged conversions (one launch).
// ---------------------------------------------------------------------------
static __device__ __forceinline__ void transpose_tile(
    const float* __restrict__ src, unsigned short* __restrict__ dst, int R,
    int C, int bx, int by, float* tile /* [64][65] */) {
  const int t = threadIdx.x;
  const int bc = bx * 64, br = by * 64;
#pragma unroll
  for (int i = 0; i < 16; ++i) {
    int idx = i * 256 + t;
    int r = idx >> 6, c = idx & 63;
    tile[r * 65 + c] = src[(size_t)(br + r) * C + bc + c];
  }
  __syncthreads();
#pragma unroll
  for (int i = 0; i < 16; ++i) {
    int idx = i * 256 + t;
    int r = idx >> 6, c = idx & 63;
    dst[(size_t)(bc + r) * R + br + c] = f2bf(tile[c * 65 + r]);
  }
}

__global__ __launch_bounds__(256) void convert_all(
    const float* __restrict__ x, const float* __restrict__ w_qkv,
    const float* __restrict__ w_out, unsigned short* __restrict__ xbf,
    unsigned short* __restrict__ wqkvt, unsigned short* __restrict__ woutt) {
  __shared__ float tile[64 * 65];
  const int id = blockIdx.x;
  if (id < 2048) {
    int i = (id * 256 + threadIdx.x) * 8;
    float4 a = *(const float4*)(x + i);
    float4 b = *(const float4*)(x + i + 4);
    ushort8 o;
    o[0] = f2bf(a.x); o[1] = f2bf(a.y); o[2] = f2bf(a.z); o[3] = f2bf(a.w);
    o[4] = f2bf(b.x); o[5] = f2bf(b.y); o[6] = f2bf(b.z); o[7] = f2bf(b.w);
    *(ushort8*)(xbf + i) = o;
  } else if (id < 2816) {
    int j = id - 2048;  // 48 x 16
    transpose_tile(w_qkv, wqkvt, D_DIM, 3 * D_DIM, j % 48, j / 48, tile);
  } else {
    int j = id - 2816;  // 16 x 16
    transpose_tile(w_out, woutt, D_DIM, D_DIM, j % 16, j / 16, tile);
  }
}

// ---------------------------------------------------------------------------
// qkv GEMM (measured-best 41.4us structure). ONE CHANGE: q scale now folds
// log2(e) so attention can use exp2 (raw v_exp_f32):
//   mul_q = 0.125 * 1.44269504 = 0.18033688
// Epilogue: q,k bf16 [B,H,T,64], v^T bf16 [B,H,64,T].
// ---------------------------------------------------------------------------
__global__ __launch_bounds__(512) void gemm_qkv_8p(
    const unsigned short* __restrict__ A, const unsigned short* __restrict__ Bt,
    const float* __restrict__ bias, unsigned short* __restrict__ qo,
    unsigned short* __restrict__ ko, unsigned short* __restrict__ vto) {
  __shared__ unsigned short As[2][256 * 64];  // 2 x 32 KB
  __shared__ unsigned short Bs[2][192 * 64];  // 2 x 24 KB

  const int tid = threadIdx.x;
  const int w = tid >> 6, l = tid & 63;
  const int wr = w >> 2, wc = w & 3;  // 2M x 4N waves, per-wave 128x48
  const int l15 = l & 15, kslc = l >> 4;

  const int id = blockIdx.x;
  const int wg = (id & 7) * 32 + (id >> 3);
  const int bx = wg & 15, by = wg >> 4;
  const int r0 = by * 256, c0 = bx * 192;

  const unsigned short* Ag = A + (size_t)r0 * KDIM;
  const unsigned short* Bg = Bt + (size_t)c0 * KDIM;

  f32x4 acc[8][3];
#pragma unroll
  for (int i = 0; i < 8; ++i)
#pragma unroll
    for (int j = 0; j < 3; ++j) acc[i][j] = (f32x4){0.f, 0.f, 0.f, 0.f};

  const int grow = tid >> 3;                 // row within 64-row chunk
  const int gcol = (tid & 7) ^ (grow & 7);   // pre-swizzled source slot

#define STAGE_A(T, BUF, CH)                                                    \
  gl_lds16(Ag + (size_t)((CH)*64 + grow) * KDIM + (T)*64 + gcol * 8,           \
           (char*)&As[BUF][0] + (CH)*8192 + w * 1024)
#define STAGE_B(T, BUF, CH)                                                    \
  gl_lds16(Bg + (size_t)((CH)*64 + grow) * KDIM + (T)*64 + gcol * 8,           \
           (char*)&Bs[BUF][0] + (CH)*8192 + w * 1024)

#define LDA(CB, mi, ks)                                                        \
  (*(const bf16x8*)((const char*)&As[CB][0] +                                  \
                    (wr * 128 + (mi)*16 + l15) * 128 +                         \
                    ((((ks)*4 + kslc) ^ (l15 & 7)) << 4)))
#define LDB(CB, ni, ks)                                                        \
  (*(const bf16x8*)((const char*)&Bs[CB][0] +                                  \
                    (wc * 48 + (ni)*16 + l15) * 128 +                          \
                    ((((ks)*4 + kslc) ^ (l15 & 7)) << 4)))

#define CLUSTER12(B_, A0, A1, A2, A3, B0, B1, B2)                              \
  do {                                                                         \
    __builtin_amdgcn_s_setprio(1);                                             \
    acc[B_ + 0][0] = MFMA16(A0, B0, acc[B_ + 0][0]);                           \
    acc[B_ + 0][1] = MFMA16(A0, B1, acc[B_ + 0][1]);                           \
    acc[B_ + 0][2] = MFMA16(A0, B2, acc[B_ + 0][2]);                           \
    acc[B_ + 1][0] = MFMA16(A1, B0, acc[B_ + 1][0]);                           \
    acc[B_ + 1][1] = MFMA16(A1, B1, acc[B_ + 1][1]);                           \
    acc[B_ + 1][2] = MFMA16(A1, B2, acc[B_ + 1][2]);                           \
    acc[B_ + 2][0] = MFMA16(A2, B0, acc[B_ + 2][0]);                           \
    acc[B_ + 2][1] = MFMA16(A2, B1, acc[B_ + 2][1]);                           \
    acc[B_ + 2][2] = MFMA16(A2, B2, acc[B_ + 2][2]);                           \
    acc[B_ + 3][0] = MFMA16(A3, B0, acc[B_ + 3][0]);                           \
    acc[B_ + 3][1] = MFMA16(A3, B1, acc[B_ + 3][1]);                           \
    acc[B_ + 3][2] = MFMA16(A3, B2, acc[B_ + 3][2]);                           \
    __builtin_amdgcn_s_setprio(0);                                             \
  } while (0)

  STAGE_A(0, 0, 0); STAGE_A(0, 0, 1); STAGE_A(0, 0, 2); STAGE_A(0, 0, 3);
  STAGE_B(0, 0, 0); STAGE_B(0, 0, 1); STAGE_B(0, 0, 2);

#pragma unroll 1
  for (int t = 0; t < 15; ++t) {
    const int cb = t & 1, nb = cb ^ 1;
    STAGE_A(t + 1, nb, 0); STAGE_A(t + 1, nb, 1);
    asm volatile("s_waitcnt vmcnt(2)" ::: "memory");
    __builtin_amdgcn_s_barrier();
    {
      bf16x8 a0 = LDA(cb, 0, 0), a1 = LDA(cb, 1, 0), a2 = LDA(cb, 2, 0),
             a3 = LDA(cb, 3, 0);
      bf16x8 b0 = LDB(cb, 0, 0), b1 = LDB(cb, 1, 0), b2 = LDB(cb, 2, 0);
      CLUSTER12(0, a0, a1, a2, a3, b0, b1, b2);
      __builtin_amdgcn_s_barrier();
      bf16x8 a4 = LDA(cb, 4, 0), a5 = LDA(cb, 5, 0), a6 = LDA(cb, 6, 0),
             a7 = LDA(cb, 7, 0);
      STAGE_A(t + 1, nb, 2); STAGE_A(t + 1, nb, 3);
      __builtin_amdgcn_s_barrier();
      CLUSTER12(4, a4, a5, a6, a7, b0, b1, b2);
      __builtin_amdgcn_s_barrier();
      bf16x8 c0_ = LDA(cb, 0, 1), c1_ = LDA(cb, 1, 1), c2_ = LDA(cb, 2, 1),
             c3_ = LDA(cb, 3, 1);
      bf16x8 d0 = LDB(cb, 0, 1), d1 = LDB(cb, 1, 1), d2 = LDB(cb, 2, 1);
      STAGE_B(t + 1, nb, 0); STAGE_B(t + 1, nb, 1);
      __builtin_amdgcn_s_barrier();
      CLUSTER12(0, c0_, c1_, c2_, c3_, d0, d1, d2);
      __builtin_amdgcn_s_barrier();
      bf16x8 c4 = LDA(cb, 4, 1), c5 = LDA(cb, 5, 1), c6 = LDA(cb, 6, 1),
             c7 = LDA(cb, 7, 1);
      STAGE_B(t + 1, nb, 2);
      __builtin_amdgcn_s_barrier();
      CLUSTER12(4, c4, c5, c6, c7, d0, d1, d2);
      __builtin_amdgcn_s_barrier();
    }
  }
  asm volatile("s_waitcnt vmcnt(0)" ::: "memory");
  __builtin_amdgcn_s_barrier();
  {
    bf16x8 a0 = LDA(1, 0, 0), a1 = LDA(1, 1, 0), a2 = LDA(1, 2, 0),
           a3 = LDA(1, 3, 0);
    bf16x8 b0 = LDB(1, 0, 0), b1 = LDB(1, 1, 0), b2 = LDB(1, 2, 0);
    CLUSTER12(0, a0, a1, a2, a3, b0, b1, b2);
    bf16x8 a4 = LDA(1, 4, 0), a5 = LDA(1, 5, 0), a6 = LDA(1, 6, 0),
           a7 = LDA(1, 7, 0);
    CLUSTER12(4, a4, a5, a6, a7, b0, b1, b2);
    bf16x8 c0_ = LDA(1, 0, 1), c1_ = LDA(1, 1, 1), c2_ = LDA(1, 2, 1),
           c3_ = LDA(1, 3, 1);
    bf16x8 d0 = LDB(1, 0, 1), d1 = LDB(1, 1, 1), d2 = LDB(1, 2, 1);
    CLUSTER12(0, c0_, c1_, c2_, c3_, d0, d1, d2);
    bf16x8 c4 = LDA(1, 4, 1), c5 = LDA(1, 5, 1), c6 = LDA(1, 6, 1),
           c7 = LDA(1, 7, 1);
    CLUSTER12(4, c4, c5, c6, c7, d0, d1, d2);
  }
#undef STAGE_A
#undef STAGE_B
#undef LDA
#undef LDB
#undef CLUSTER12

#pragma unroll
  for (int ni = 0; ni < 3; ++ni) {
    const int col0 = c0 + wc * 48 + ni * 16;
    const int which = col0 >> 10;  // 0=q,1=k,2=v
    const int h = (col0 >> 6) & 15;
    const int dh = (col0 & 63) + l15;
    const float bv = bias[col0 + l15];
#pragma unroll
    for (int mi = 0; mi < 8; ++mi) {
      int row = r0 + wr * 128 + mi * 16 + (l >> 4) * 4;  // multiple of 4
      int b_ = row >> 11, t0 = row & 2047;
      if (which == 2) {
        u16x4 pk;
#pragma unroll
        for (int j = 0; j < 4; ++j) pk[j] = f2bf(acc[mi][ni][j] + bv);
        *(u16x4*)(vto + ((size_t)(b_ * H_N + h) * DH_N + dh) * T_DIM + t0) = pk;
      } else {
        // q carries SCALE * log2(e) so attention uses exp2 directly
        float mul = (which == 0) ? 0.18033688f : 1.0f;
        unsigned short* dst = (which == 0) ? qo : ko;
#pragma unroll
        for (int j = 0; j < 4; ++j)
          dst[((size_t)(b_ * H_N + h) * T_DIM + t0 + j) * DH_N + dh] =
              f2bf((acc[mi][ni][j] + bv) * mul);
      }
    }
  }
}

// ---------------------------------------------------------------------------
// out-proj GEMM (unchanged).
// ---------------------------------------------------------------------------
__global__ __launch_bounds__(256) void gemm_out_p4(
    const unsigned short* __restrict__ A, const unsigned short* __restrict__ Bt,
    const float* __restrict__ bias, float* __restrict__ fo) {
  __shared__ unsigned short As[4][4096];
  __shared__ unsigned short Bs[4][4096];

  const int tid = threadIdx.x;
  const int w = tid >> 6, l = tid & 63;
  const int wr = w >> 1, wc = w & 1;
  const int l15 = l & 15, kslc = l >> 4;

  const int id = blockIdx.x;
  const int wg = (id & 7) * 32 + (id >> 3);
  const int bx = wg & 7, by = wg >> 3;
  const int r0 = by * 128, c0 = bx * 128;

  const unsigned short* Ag = A + (size_t)r0 * KDIM;
  const unsigned short* Bg = Bt + (size_t)c0 * KDIM;

  f32x4 acc[4][4];
#pragma unroll
  for (int i = 0; i < 4; ++i)
#pragma unroll
    for (int j = 0; j < 4; ++j) acc[i][j] = (f32x4){0.f, 0.f, 0.f, 0.f};

  const int srow = l >> 2;
  const int srcslot = (l & 3) ^ ((l >> 3) & 3);

#define STAGE_O(T, BUF)                                                        \
  do {                                                                         \
    const size_t kk0 = (size_t)(T) * 32;                                       \
    gl_lds16(Ag + (size_t)(w * 16 + srow) * KDIM + kk0 + srcslot * 8,          \
             (char*)&As[BUF][0] + w * 1024);                                   \
    gl_lds16(Ag + (size_t)(64 + w * 16 + srow) * KDIM + kk0 + srcslot * 8,     \
             (char*)&As[BUF][0] + (4 + w) * 1024);                             \
    gl_lds16(Bg + (size_t)(w * 16 + srow) * KDIM + kk0 + srcslot * 8,          \
             (char*)&Bs[BUF][0] + w * 1024);                                   \
    gl_lds16(Bg + (size_t)(64 + w * 16 + srow) * KDIM + kk0 + srcslot * 8,     \
             (char*)&Bs[BUF][0] + (4 + w) * 1024);                             \
  } while (0)

#define OCOMPUTE(CB)                                                           \
  do {                                                                         \
    bf16x8 af[4], bfr[4];                                                      \
    _Pragma("unroll") for (int mi = 0; mi < 4; ++mi) {                         \
      int row = wr * 64 + mi * 16 + l15;                                       \
      af[mi] = *(const bf16x8*)((const char*)&As[CB][0] + row * 64 +           \
                                ((kslc ^ ((row >> 1) & 3)) << 4));             \
    }                                                                          \
    _Pragma("unroll") for (int ni = 0; ni < 4; ++ni) {                         \
      int row = wc * 64 + ni * 16 + l15;                                       \
      bfr[ni] = *(const bf16x8*)((const char*)&Bs[CB][0] + row * 64 +          \
                                 ((kslc ^ ((row >> 1) & 3)) << 4));            \
    }                                                                          \
    __builtin_amdgcn_s_setprio(1);                                             \
    _Pragma("unroll") for (int mi = 0; mi < 4; ++mi)                           \
        _Pragma("unroll") for (int ni = 0; ni < 4; ++ni) acc[mi][ni] =         \
            MFMA16(af[mi], bfr[ni], acc[mi][ni]);                              \
    __builtin_amdgcn_s_setprio(0);                                             \
  } while (0)

  STAGE_O(0, 0);
  STAGE_O(1, 1);

  for (int t = 0; t < 30; ++t) {
    STAGE_O(t + 2, (t + 2) & 3);
    asm volatile("s_waitcnt vmcnt(8)" ::: "memory");
    __builtin_amdgcn_s_barrier();
    OCOMPUTE(t & 3);
  }
  asm volatile("s_waitcnt vmcnt(4)" ::: "memory");
  __builtin_amdgcn_s_barrier();
  OCOMPUTE(2);
  asm volatile("s_waitcnt vmcnt(0)" ::: "memory");
  __builtin_amdgcn_s_barrier();
  OCOMPUTE(3);
#undef STAGE_O
#undef OCOMPUTE

#pragma unroll
  for (int mi = 0; mi < 4; ++mi) {
#pragma unroll
    for (int ni = 0; ni < 4; ++ni) {
      int row = r0 + wr * 64 + mi * 16 + (l >> 4) * 4;
      int col = c0 + wc * 64 + ni * 16 + l15;
      float bv = bias[col];
#pragma unroll
      for (int j = 0; j < 4; ++j)
        fo[(size_t)(row + j) * D_DIM + col] = acc[mi][ni][j] + bv;
    }
  }
}

// ---------------------------------------------------------------------------
// attn_ilp2: no LDS, no barriers. Each wave owns 32 q-rows as TWO
// independent 16-row chains (A/B) that SHARE every K/V fragment:
// 2x MFMA per load, two interleaved softmax chains hide each other's
// latency. Interior tiles skip masking entirely; softmax uses exp2
// (q carries log2e) and depth-4 tree reductions.
// Grid 512: bh = (bid&7)*4 + ((bid>>3)&3) (4 bh per XCD, L2-resident),
// qt128 = bid>>5; wave w covers rows qt128*128 + w*32 + 0..31.
// ---------------------------------------------------------------------------
__global__ __launch_bounds__(256) void attn_ilp2(
    const unsigned short* __restrict__ qbf,
    const unsigned short* __restrict__ kbf,
    const unsigned short* __restrict__ vtbf,
    unsigned short* __restrict__ ctx) {
  const int tid = threadIdx.x;
  const int w = tid >> 6, l = tid & 63;
  const int g = l >> 4, ln = l & 15;

  const int bid = blockIdx.x;
  const int bh = (bid & 7) * 4 + ((bid >> 3) & 3);  // 0..31
  const int qt = bid >> 5;                          // 0..15
  const int qw0 = qt * 128 + w * 32;                // wave's 32 q rows
  const int qA = qw0 + ln;
  const int qB = qw0 + 16 + ln;

  const unsigned short* kp = kbf + (size_t)bh * T_DIM * DH_N;
  const unsigned short* vtp = vtbf + (size_t)bh * DH_N * T_DIM;

  bf16x8 qfA0, qfA1, qfB0, qfB1;
  {
    const unsigned short* qpA = qbf + ((size_t)bh * T_DIM + qA) * DH_N;
    qfA0 = *(const bf16x8*)(qpA + g * 8);
    qfA1 = *(const bf16x8*)(qpA + 32 + g * 8);
    const unsigned short* qpB = qbf + ((size_t)bh * T_DIM + qB) * DH_N;
    qfB0 = *(const bf16x8*)(qpB + g * 8);
    qfB1 = *(const bf16x8*)(qpB + 32 + g * 8);
  }

#define KAP(row) \
  (32 * (((row) >> 4) & 1) + 8 * (((row)&15) >> 2) + 4 * ((row) >> 5) + ((row)&3))
  const unsigned short* kbase[4];
#pragma unroll
  for (int nk = 0; nk < 4; ++nk) {
    int rrow = nk * 16 + ln;
    kbase[nk] = kp + (size_t)KAP(rrow) * DH_N + g * 8;
  }
  const unsigned short* vbase[4];
#pragma unroll
  for (int nd = 0; nd < 4; ++nd)
    vbase[nd] = vtp + (size_t)(nd * 16 + ln) * T_DIM + g * 8;
#undef KAP

  f32x4 accA[4], accB[4];
#pragma unroll
  for (int nd = 0; nd < 4; ++nd) {
    accA[nd] = (f32x4){0.f, 0.f, 0.f, 0.f};
    accB[nd] = (f32x4){0.f, 0.f, 0.f, 0.f};
  }
  float mA = -1e30f, lsA = 0.f, mB = -1e30f, lsB = 0.f;

  const int ktl = (qw0 >= WIN) ? ((qw0 - WIN) & ~63) : 0;
  const int kth = qw0 & ~63;

// masked max: clamp (if MASKED) + depth-4 tree + 2 shuffles
#define MASK_MAX(S, P, TM, QABS, KT, MASKED)                                   \
  do {                                                                         \
    _Pragma("unroll") for (int nk = 0; nk < 4; ++nk)                           \
        _Pragma("unroll") for (int j = 0; j < 4; ++j) {                        \
      float s_ = S[nk][j];                                                     \
      if (MASKED) {                                                            \
        int k_abs = (KT) + 32 * (nk & 1) + 8 * g + 4 * (nk >> 1) + j;          \
        bool ok = (k_abs <= (QABS)) && (k_abs + WIN >= (QABS));                \
        s_ = ok ? s_ : -1e30f;                                                 \
      }                                                                        \
      P[nk][j] = s_;                                                           \
    }                                                                          \
    float a0 = fmaxf(P[0][0], P[0][1]), a1 = fmaxf(P[0][2], P[0][3]);          \
    float a2 = fmaxf(P[1][0], P[1][1]), a3 = fmaxf(P[1][2], P[1][3]);          \
    float a4 = fmaxf(P[2][0], P[2][1]), a5 = fmaxf(P[2][2], P[2][3]);          \
    float a6 = fmaxf(P[3][0], P[3][1]), a7 = fmaxf(P[3][2], P[3][3]);          \
    TM = fmaxf(fmaxf(fmaxf(a0, a1), fmaxf(a2, a3)),                            \
               fmaxf(fmaxf(a4, a5), fmaxf(a6, a7)));                           \
    TM = fmaxf(TM, __shfl_xor(TM, 16, 64));                                    \
    TM = fmaxf(TM, __shfl_xor(TM, 32, 64));                                    \
  } while (0)

// online update (exp2 domain) + bf16 pack
#define ONLINE(P, TM, M, LS, ACC, PK)                                          \
  do {                                                                         \
    float mn = fmaxf(M, TM);                                                   \
    float sc = exp2f(M - mn);                                                  \
    _Pragma("unroll") for (int nk = 0; nk < 4; ++nk)                           \
        _Pragma("unroll") for (int j = 0; j < 4; ++j)                          \
            P[nk][j] = exp2f(P[nk][j] - mn);                                   \
    float s0 = (P[0][0] + P[0][1]) + (P[0][2] + P[0][3]);                      \
    float s1 = (P[1][0] + P[1][1]) + (P[1][2] + P[1][3]);                      \
    float s2 = (P[2][0] + P[2][1]) + (P[2][2] + P[2][3]);                      \
    float s3 = (P[3][0] + P[3][1]) + (P[3][2] + P[3][3]);                      \
    float ps = (s0 + s1) + (s2 + s3);                                          \
    ps += __shfl_xor(ps, 16, 64);                                              \
    ps += __shfl_xor(ps, 32, 64);                                              \
    LS = LS * sc + ps;                                                         \
    M = mn;                                                                    \
    _Pragma("unroll") for (int nd = 0; nd < 4; ++nd) {                         \
      ACC[nd][0] *= sc; ACC[nd][1] *= sc; ACC[nd][2] *= sc; ACC[nd][3] *= sc;  \
    }                                                                          \
    _Pragma("unroll") for (int nk = 0; nk < 4; ++nk) {                         \
      PK[nk][0] = (unsigned)f2bf(P[nk][0]) | ((unsigned)f2bf(P[nk][1]) << 16); \
      PK[nk][1] = (unsigned)f2bf(P[nk][2]) | ((unsigned)f2bf(P[nk][3]) << 16); \
    }                                                                          \
  } while (0)

#define TILE_BODY(KT, MASKED)                                                  \
  do {                                                                         \
    f32x4 sA[4], sB[4];                                                        \
    _Pragma("unroll") for (int nk = 0; nk < 4; ++nk) {                         \
      sA[nk] = (f32x4){0.f, 0.f, 0.f, 0.f};                                    \
      sB[nk] = (f32x4){0.f, 0.f, 0.f, 0.f};                                    \
    }                                                                          \
    _Pragma("unroll") for (int ks = 0; ks < 2; ++ks) {                         \
      bf16x8 qa = ks ? qfA1 : qfA0;                                            \
      bf16x8 qb = ks ? qfB1 : qfB0;                                            \
      _Pragma("unroll") for (int nk = 0; nk < 4; ++nk) {                       \
        bf16x8 kf = *(const bf16x8*)(kbase[nk] + (size_t)(KT)*DH_N + ks * 32); \
        sA[nk] = MFMA16(kf, qa, sA[nk]);                                       \
        sB[nk] = MFMA16(kf, qb, sB[nk]);                                       \
      }                                                                        \
    }                                                                          \
    float pA[4][4], pB[4][4];                                                  \
    float tmA, tmB;                                                            \
    MASK_MAX(sA, pA, tmA, qA, KT, MASKED);                                     \
    MASK_MAX(sB, pB, tmB, qB, KT, MASKED);                                     \
    unsigned int pkA[4][2], pkB[4][2];                                         \
    ONLINE(pA, tmA, mA, lsA, accA, pkA);                                       \
    ONLINE(pB, tmB, mB, lsB, accB, pkB);                                       \
    _Pragma("unroll") for (int ks = 0; ks < 2; ++ks) {                         \
      union { unsigned int d[4]; bf16x8 v; } pfA, pfB;                         \
      pfA.d[0] = pkA[ks][0];     pfA.d[1] = pkA[ks][1];                        \
      pfA.d[2] = pkA[2 + ks][0]; pfA.d[3] = pkA[2 + ks][1];                    \
      pfB.d[0] = pkB[ks][0];     pfB.d[1] = pkB[ks][1];                        \
      pfB.d[2] = pkB[2 + ks][0]; pfB.d[3] = pkB[2 + ks][1];                    \
      _Pragma("unroll") for (int nd = 0; nd < 4; ++nd) {                       \
        bf16x8 vf = *(const bf16x8*)(vbase[nd] + (KT) + ks * 32);              \
        accA[nd] = MFMA16(vf, pfA.v, accA[nd]);                                \
        accB[nd] = MFMA16(vf, pfB.v, accB[nd]);                                \
      }                                                                        \
    }                                                                          \
  } while (0)

  for (int kt = ktl; kt <= kth; kt += 64) {
    const bool masked = (kt == kth) || (qw0 >= WIN && kt == ktl);
    if (masked) TILE_BODY(kt, 1);
    else        TILE_BODY(kt, 0);
  }
#undef TILE_BODY
#undef ONLINE
#undef MASK_MAX

  const int b_ = bh >> 4, h = bh & 15;
  {
    float inv = 1.f / lsA;
    unsigned short* op = ctx + ((size_t)b_ * T_DIM + qA) * D_DIM + h * DH_N;
#pragma unroll
    for (int nd = 0; nd < 4; ++nd) {
      u16x4 o;
#pragma unroll
      for (int j = 0; j < 4; ++j) o[j] = f2bf(accA[nd][j] * inv);
      *(u16x4*)(op + nd * 16 + g * 4) = o;
    }
  }
  {
    float inv = 1.f / lsB;
    unsigned short* op = ctx + ((size_t)b_ * T_DIM + qB) * D_DIM + h * DH_N;
#pragma unroll
    for (int nd = 0; nd < 4; ++nd) {
      u16x4 o;
#pragma unroll
      for (int j = 0; j < 4; ++j) o[j] = f2bf(accB[nd][j] * inv);
      *(u16x4*)(op + nd * 16 + g * 4) = o;
    }
  }
}

// ---------------------------------------------------------------------------
extern "C" void kernel_launch(void* const* d_in, const int* in_sizes, int n_in,
                              void* d_out, int out_size, void* d_ws,
                              size_t ws_size, hipStream_t stream) {
  const float* x = (const float*)d_in[0];
  const float* w_qkv = (const float*)d_in[1];
  const float* b_qkv = (const float*)d_in[2];
  const float* w_out = (const float*)d_in[3];
  const float* b_out = (const float*)d_in[4];
  float* out = (float*)d_out;

  const size_t per = (size_t)BN * H_N * T_DIM * DH_N;  // 4,194,304
  unsigned short* qbf = (unsigned short*)d_ws;
  unsigned short* kbf = qbf + per;
  unsigned short* vtbf = kbf + per;                    // [B,H,64,T]
  unsigned short* xbf = vtbf + per;                    // [4096][1024]
  unsigned short* wqkvt = xbf + (size_t)NROWS * D_DIM; // [3072][1024]
  unsigned short* woutt = wqkvt + (size_t)3 * D_DIM * D_DIM;  // [1024][1024]
  unsigned short* ctxbf = woutt + (size_t)D_DIM * D_DIM;      // [4096][1024]

  convert_all<<<dim3(3072), dim3(256), 0, stream>>>(x, w_qkv, w_out, xbf,
                                                    wqkvt, woutt);

  gemm_qkv_8p<<<dim3(256), dim3(512), 0, stream>>>(xbf, wqkvt, b_qkv, qbf, kbf,
                                                   vtbf);

  // 512 blocks: 32 bh x 16 q-tiles(128 rows), 4 waves x 32 rows each
  attn_ilp2<<<dim3(512), dim3(256), 0, stream>>>(qbf, kbf, vtbf, ctxbf);

  gemm_out_p4<<<dim3(256), dim3(256), 0, stream>>>(ctxbf, woutt, b_out, out);
}